// Round 4
// baseline (1444.811 us; speedup 1.0000x reference)
//
#include <hip/hip_runtime.h>
#include <hip/hip_fp16.h>

#define N_NODES 200000
#define F_IN 128
#define HID 16
#define SHIFT 7
#define BKT_NODES 128                 // 1 << SHIFT
#define NB 1563                       // ceil(N_NODES / 128)
#define NBLK 256                      // hist/partition grid size
#define BLKT 512                      // hist/partition block threads
#define M_SCAN (NB * NBLK)            // 400128 (divisible by 256)
#define PAD 17                        // LDS acc row stride (bank spread)
#define UNROLL 8

// ---------------- Stage 1: h = x @ W1 -> fp16 [N,16] -----------------------
__global__ __launch_bounds__(256) void gemm1_kernel(const float* __restrict__ x,
                                                    const float* __restrict__ W1,
                                                    __half* __restrict__ h) {
    __shared__ float w[F_IN * HID];  // 8 KB
    int tid = threadIdx.x;
    for (int i = tid; i < F_IN * HID; i += 256) w[i] = W1[i];
    __syncthreads();

    int row = blockIdx.x * 256 + tid;
    if (row >= N_NODES) return;

    float acc[HID];
#pragma unroll
    for (int j = 0; j < HID; j++) acc[j] = 0.f;

    const float4* xr = reinterpret_cast<const float4*>(x + (size_t)row * F_IN);
#pragma unroll 4
    for (int k4 = 0; k4 < F_IN / 4; k4++) {
        float4 xv = xr[k4];
        const float* wr = &w[k4 * 4 * HID];
#pragma unroll
        for (int j = 0; j < HID; j++) acc[j] += xv.x * wr[j];
#pragma unroll
        for (int j = 0; j < HID; j++) acc[j] += xv.y * wr[HID + j];
#pragma unroll
        for (int j = 0; j < HID; j++) acc[j] += xv.z * wr[2 * HID + j];
#pragma unroll
        for (int j = 0; j < HID; j++) acc[j] += xv.w * wr[3 * HID + j];
    }

    union { __half hh[16]; uint4 u[2]; } pk;
#pragma unroll
    for (int j = 0; j < HID; j++) pk.hh[j] = __float2half(acc[j]);
    uint4* hr = reinterpret_cast<uint4*>(h + (size_t)row * HID);
    hr[0] = pk.u[0];
    hr[1] = pk.u[1];
}

// ---------------- Bucket histogram: hist[b][blk] ----------------------------
__global__ __launch_bounds__(BLKT) void hist_kernel(const int* __restrict__ dst,
                                                    int* __restrict__ hist,
                                                    int n_edges, int chunk) {
    __shared__ int hc[NB];  // 6.3 KB
    int t = threadIdx.x, blk = blockIdx.x;
    for (int i = t; i < NB; i += BLKT) hc[i] = 0;
    __syncthreads();
    int e0 = blk * chunk;
    int e1 = e0 + chunk; if (e1 > n_edges) e1 = n_edges;
    for (int e = e0 + t; e < e1; e += BLKT)
        atomicAdd(&hc[dst[e] >> SHIFT], 1);
    __syncthreads();
    for (int b = t; b < NB; b += BLKT) hist[b * NBLK + blk] = hc[b];
}

// ---------------- 3-level exclusive scan over M_SCAN elements ---------------
__global__ __launch_bounds__(256) void scan1_kernel(const int* __restrict__ in,
                                                    int* __restrict__ out,
                                                    int* __restrict__ bsum, int n) {
    __shared__ int s[256];
    int t = threadIdx.x, i = blockIdx.x * 256 + t;
    int v = (i < n) ? in[i] : 0;
    s[t] = v; __syncthreads();
    for (int off = 1; off < 256; off <<= 1) {
        int u = (t >= off) ? s[t - off] : 0; __syncthreads();
        s[t] += u; __syncthreads();
    }
    if (i < n) out[i] = s[t] - v;  // block-local exclusive
    if (t == 255) bsum[blockIdx.x] = s[255];
}

__global__ __launch_bounds__(256) void scan2_kernel(int* __restrict__ bsum, int nb) {
    __shared__ int s[256];
    __shared__ int carry;
    int t = threadIdx.x;
    if (t == 0) carry = 0;
    __syncthreads();
    for (int base = 0; base < nb; base += 256) {
        int v = (base + t < nb) ? bsum[base + t] : 0;
        s[t] = v; __syncthreads();
        for (int off = 1; off < 256; off <<= 1) {
            int u = (t >= off) ? s[t - off] : 0; __syncthreads();
            s[t] += u; __syncthreads();
        }
        if (base + t < nb) bsum[base + t] = carry + s[t] - v;  // exclusive
        __syncthreads();
        if (t == 0) carry += s[255];
        __syncthreads();
    }
}

__global__ __launch_bounds__(256) void scan3_kernel(int* __restrict__ out,
                                                    const int* __restrict__ bsum,
                                                    int n, int total) {
    int i = blockIdx.x * 256 + threadIdx.x;
    if (i < n) out[i] += bsum[blockIdx.x];
    if (i == 0) out[n] = total;
}

// ---------------- Partition: bucket-grouped records --------------------------
// record: {src | local_dst<<18, weight_bits}
__global__ __launch_bounds__(BLKT) void partition_kernel(const int* __restrict__ src,
                                                         const int* __restrict__ dst,
                                                         const float* __restrict__ ew,
                                                         const int* __restrict__ scanned,
                                                         int2* __restrict__ recs,
                                                         int n_edges, int chunk) {
    __shared__ int cur[NB];
    int t = threadIdx.x, blk = blockIdx.x;
    for (int b = t; b < NB; b += BLKT) cur[b] = scanned[b * NBLK + blk];
    __syncthreads();
    int e0 = blk * chunk;
    int e1 = e0 + chunk; if (e1 > n_edges) e1 = n_edges;
    for (int e = e0 + t; e < e1; e += BLKT) {
        int d = dst[e];
        int b = d >> SHIFT;
        int pos = atomicAdd(&cur[b], 1);  // LDS atomic, block-private range
        recs[pos] = make_int2(src[e] | ((d & (BKT_NODES - 1)) << 18),
                              __float_as_int(ew[e]));
    }
}

// ---------------- Aggregation per bucket, LDS accumulator, unroll-8 ---------
// Inner engine shared by both layers: 2 lanes per record (16 B fp16 each).
// layer 1: h2 = relu(agg + b1) @ W2   (fp16 out)
__global__ __launch_bounds__(256) void agg_mid_kernel(const __half* __restrict__ h,
                                                      const int* __restrict__ scanned,
                                                      const int2* __restrict__ recs,
                                                      const float* __restrict__ b1,
                                                      const float* __restrict__ W2,
                                                      __half* __restrict__ h2) {
    __shared__ float acc[BKT_NODES * PAD];  // 8.7 KB
    __shared__ float wm[HID * HID];
    __shared__ float bs[HID];
    int t = threadIdx.x, bkt = blockIdx.x;
    for (int i = t; i < BKT_NODES * PAD; i += 256) acc[i] = 0.f;
    if (t < HID * HID) wm[t] = W2[t];
    if (t < HID) bs[t] = b1[t];
    __syncthreads();

    int beg = scanned[bkt * NBLK];
    int end = scanned[(bkt + 1) * NBLK];
    int slot = t >> 1, q = t & 1;           // 128 slots x 2 lanes
    for (int p0 = beg + slot; p0 < end; p0 += 128 * UNROLL) {
        int2 r[UNROLL];
        uint4 g[UNROLL];
        float wv[UNROLL];
#pragma unroll
        for (int u = 0; u < UNROLL; u++) {
            int pp = p0 + u * 128;
            bool v = pp < end;
            int2 rr = recs[v ? pp : beg];
            r[u] = rr;
            wv[u] = v ? __int_as_float(rr.y) : 0.f;
        }
#pragma unroll
        for (int u = 0; u < UNROLL; u++) {
            int s = r[u].x & 0x3FFFF;
            g[u] = *reinterpret_cast<const uint4*>(h + (size_t)s * HID + q * 8);
        }
#pragma unroll
        for (int u = 0; u < UNROLL; u++) {
            int ld = ((unsigned)r[u].x) >> 18;
            float w = wv[u];
            const __half2* hh = reinterpret_cast<const __half2*>(&g[u]);
            float* a = &acc[ld * PAD + q * 8];
#pragma unroll
            for (int j = 0; j < 4; j++) {
                float2 f = __half22float2(hh[j]);
                atomicAdd(&a[2 * j],     f.x * w);
                atomicAdd(&a[2 * j + 1], f.y * w);
            }
        }
    }
    __syncthreads();

    int base = bkt * BKT_NODES;
    for (int i = t; i < BKT_NODES * HID; i += 256) {
        int n = i >> 4, f = i & 15;
        int node = base + n;
        if (node < N_NODES) {
            float sum = 0.f;
#pragma unroll
            for (int k = 0; k < HID; k++)
                sum += fmaxf(acc[n * PAD + k] + bs[k], 0.f) * wm[k * HID + f];
            h2[(size_t)node * HID + f] = __float2half(sum);
        }
    }
}

// layer 2: out = relu(agg + b2) @ Wd + bd   (fp32 out)
__global__ __launch_bounds__(256) void agg_final_kernel(const __half* __restrict__ h2,
                                                        const int* __restrict__ scanned,
                                                        const int2* __restrict__ recs,
                                                        const float* __restrict__ b2,
                                                        const float* __restrict__ Wd,
                                                        const float* __restrict__ bd,
                                                        float* __restrict__ out) {
    __shared__ float acc[BKT_NODES * PAD];
    __shared__ float wd[HID];
    __shared__ float bs[HID];
    __shared__ float bdv;
    int t = threadIdx.x, bkt = blockIdx.x;
    for (int i = t; i < BKT_NODES * PAD; i += 256) acc[i] = 0.f;
    if (t < HID) { wd[t] = Wd[t]; bs[t] = b2[t]; }
    if (t == 0) bdv = bd[0];
    __syncthreads();

    int beg = scanned[bkt * NBLK];
    int end = scanned[(bkt + 1) * NBLK];
    int slot = t >> 1, q = t & 1;
    for (int p0 = beg + slot; p0 < end; p0 += 128 * UNROLL) {
        int2 r[UNROLL];
        uint4 g[UNROLL];
        float wv[UNROLL];
#pragma unroll
        for (int u = 0; u < UNROLL; u++) {
            int pp = p0 + u * 128;
            bool v = pp < end;
            int2 rr = recs[v ? pp : beg];
            r[u] = rr;
            wv[u] = v ? __int_as_float(rr.y) : 0.f;
        }
#pragma unroll
        for (int u = 0; u < UNROLL; u++) {
            int s = r[u].x & 0x3FFFF;
            g[u] = *reinterpret_cast<const uint4*>(h2 + (size_t)s * HID + q * 8);
        }
#pragma unroll
        for (int u = 0; u < UNROLL; u++) {
            int ld = ((unsigned)r[u].x) >> 18;
            float w = wv[u];
            const __half2* hh = reinterpret_cast<const __half2*>(&g[u]);
            float* a = &acc[ld * PAD + q * 8];
#pragma unroll
            for (int j = 0; j < 4; j++) {
                float2 f = __half22float2(hh[j]);
                atomicAdd(&a[2 * j],     f.x * w);
                atomicAdd(&a[2 * j + 1], f.y * w);
            }
        }
    }
    __syncthreads();

    int node = bkt * BKT_NODES + t;
    if (t < BKT_NODES && node < N_NODES) {
        float s = bdv;
#pragma unroll
        for (int k = 0; k < HID; k++)
            s += fmaxf(acc[t * PAD + k] + bs[k], 0.f) * wd[k];
        out[node] = s;
    }
}

// =================== Fallback path (R1, fp32): atomic scatter ===============
__global__ __launch_bounds__(256) void gemm1f_kernel(const float* __restrict__ x,
                                                     const float* __restrict__ W1,
                                                     float* __restrict__ h) {
    __shared__ float w[F_IN * HID];
    int tid = threadIdx.x;
    for (int i = tid; i < F_IN * HID; i += 256) w[i] = W1[i];
    __syncthreads();
    int row = blockIdx.x * 256 + tid;
    if (row >= N_NODES) return;
    float acc[HID];
#pragma unroll
    for (int j = 0; j < HID; j++) acc[j] = 0.f;
    const float4* xr = reinterpret_cast<const float4*>(x + (size_t)row * F_IN);
#pragma unroll 4
    for (int k4 = 0; k4 < F_IN / 4; k4++) {
        float4 xv = xr[k4];
        const float* wr = &w[k4 * 4 * HID];
#pragma unroll
        for (int j = 0; j < HID; j++) acc[j] += xv.x * wr[j];
#pragma unroll
        for (int j = 0; j < HID; j++) acc[j] += xv.y * wr[HID + j];
#pragma unroll
        for (int j = 0; j < HID; j++) acc[j] += xv.z * wr[2 * HID + j];
#pragma unroll
        for (int j = 0; j < HID; j++) acc[j] += xv.w * wr[3 * HID + j];
    }
    float4* hr = reinterpret_cast<float4*>(h + (size_t)row * HID);
#pragma unroll
    for (int q = 0; q < HID / 4; q++)
        hr[q] = make_float4(acc[4 * q], acc[4 * q + 1], acc[4 * q + 2], acc[4 * q + 3]);
}

__global__ __launch_bounds__(256) void scatter_kernel(const float* __restrict__ h,
                                                      const int* __restrict__ src,
                                                      const int* __restrict__ dst,
                                                      const float* __restrict__ ew,
                                                      float* __restrict__ agg,
                                                      int n_edges) {
    long long idx = (long long)blockIdx.x * 256 + threadIdx.x;
    long long total = (long long)n_edges * HID;
    if (idx >= total) return;
    int e = (int)(idx >> 4);
    int j = (int)(idx & (HID - 1));
    float val = h[(size_t)src[e] * HID + j] * ew[e];
    atomicAdd(&agg[(size_t)dst[e] * HID + j], val);
}

__global__ __launch_bounds__(256) void gemm2_kernel(const float* __restrict__ agg,
                                                    const float* __restrict__ b1,
                                                    const float* __restrict__ W2,
                                                    float* __restrict__ h2) {
    __shared__ float w[HID * HID];
    __shared__ float bias[HID];
    int tid = threadIdx.x;
    if (tid < HID * HID) w[tid] = W2[tid];
    if (tid < HID) bias[tid] = b1[tid];
    __syncthreads();
    int row = blockIdx.x * 256 + tid;
    if (row >= N_NODES) return;
    float hv[HID];
    const float4* ar = reinterpret_cast<const float4*>(agg + (size_t)row * HID);
#pragma unroll
    for (int q = 0; q < 4; q++) {
        float4 v = ar[q];
        hv[4 * q + 0] = fmaxf(v.x + bias[4 * q + 0], 0.f);
        hv[4 * q + 1] = fmaxf(v.y + bias[4 * q + 1], 0.f);
        hv[4 * q + 2] = fmaxf(v.z + bias[4 * q + 2], 0.f);
        hv[4 * q + 3] = fmaxf(v.w + bias[4 * q + 3], 0.f);
    }
    float acc[HID];
#pragma unroll
    for (int j = 0; j < HID; j++) acc[j] = 0.f;
#pragma unroll
    for (int k = 0; k < HID; k++) {
        float hk = hv[k];
#pragma unroll
        for (int j = 0; j < HID; j++) acc[j] += hk * w[k * HID + j];
    }
    float4* hr = reinterpret_cast<float4*>(h2 + (size_t)row * HID);
#pragma unroll
    for (int q = 0; q < 4; q++)
        hr[q] = make_float4(acc[4 * q], acc[4 * q + 1], acc[4 * q + 2], acc[4 * q + 3]);
}

__global__ __launch_bounds__(256) void final_kernel(const float* __restrict__ agg,
                                                    const float* __restrict__ b2,
                                                    const float* __restrict__ Wd,
                                                    const float* __restrict__ bd,
                                                    float* __restrict__ out) {
    __shared__ float wd[HID];
    __shared__ float bias[HID];
    __shared__ float bdv;
    int tid = threadIdx.x;
    if (tid < HID) { wd[tid] = Wd[tid]; bias[tid] = b2[tid]; }
    if (tid == 0) bdv = bd[0];
    __syncthreads();
    int row = blockIdx.x * 256 + tid;
    if (row >= N_NODES) return;
    const float4* ar = reinterpret_cast<const float4*>(agg + (size_t)row * HID);
    float acc = bdv;
#pragma unroll
    for (int q = 0; q < 4; q++) {
        float4 v = ar[q];
        acc += fmaxf(v.x + bias[4 * q + 0], 0.f) * wd[4 * q + 0];
        acc += fmaxf(v.y + bias[4 * q + 1], 0.f) * wd[4 * q + 1];
        acc += fmaxf(v.z + bias[4 * q + 2], 0.f) * wd[4 * q + 2];
        acc += fmaxf(v.w + bias[4 * q + 3], 0.f) * wd[4 * q + 3];
    }
    out[row] = acc;
}

extern "C" void kernel_launch(void* const* d_in, const int* in_sizes, int n_in,
                              void* d_out, int out_size, void* d_ws, size_t ws_size,
                              hipStream_t stream) {
    const float* x    = (const float*)d_in[0];
    const int*   esrc = (const int*)d_in[1];
    const int*   edst = (const int*)d_in[2];
    const float* ew   = (const float*)d_in[3];
    const float* W1   = (const float*)d_in[4];
    const float* b1   = (const float*)d_in[5];
    const float* W2   = (const float*)d_in[6];
    const float* b2   = (const float*)d_in[7];
    const float* Wd   = (const float*)d_in[8];
    const float* bd   = (const float*)d_in[9];
    float* out = (float*)d_out;

    int n_edges = in_sizes[1];
    int num_node_blocks = (N_NODES + 255) / 256;

    // ---- workspace layout (fast path) ----
    size_t hbuf = (size_t)N_NODES * HID * sizeof(__half);      // 6.4 MB each
    size_t hist_bytes = (size_t)M_SCAN * 4;
    size_t scan_bytes = (((size_t)M_SCAN + 1) * 4 + 15) / 16 * 16;
    int scan_blocks = M_SCAN / 256;                            // 1563
    size_t bsum_bytes = (((size_t)scan_blocks * 4 + 15) / 16) * 16;
    size_t recs_bytes = (size_t)n_edges * 8;

    size_t needed = 2 * hbuf + hist_bytes + scan_bytes + bsum_bytes + recs_bytes;

    if (ws_size >= needed && n_edges > 0) {
        char* p = (char*)d_ws;
        __half* h1   = (__half*)p;  p += hbuf;
        __half* h2   = (__half*)p;  p += hbuf;
        int* hist    = (int*)p;     p += hist_bytes;
        int* scanned = (int*)p;     p += scan_bytes;
        int* bsum    = (int*)p;     p += bsum_bytes;
        int2* recs   = (int2*)p;

        int chunk = (n_edges + NBLK - 1) / NBLK;

        gemm1_kernel<<<num_node_blocks, 256, 0, stream>>>(x, W1, h1);

        hist_kernel<<<NBLK, BLKT, 0, stream>>>(edst, hist, n_edges, chunk);
        scan1_kernel<<<scan_blocks, 256, 0, stream>>>(hist, scanned, bsum, M_SCAN);
        scan2_kernel<<<1, 256, 0, stream>>>(bsum, scan_blocks);
        scan3_kernel<<<scan_blocks, 256, 0, stream>>>(scanned, bsum, M_SCAN, n_edges);
        partition_kernel<<<NBLK, BLKT, 0, stream>>>(esrc, edst, ew, scanned, recs,
                                                    n_edges, chunk);

        agg_mid_kernel<<<NB, 256, 0, stream>>>(h1, scanned, recs, b1, W2, h2);
        agg_final_kernel<<<NB, 256, 0, stream>>>(h2, scanned, recs, b2, Wd, bd, out);
    } else {
        // Fallback: R1 atomic path (fp32, needs only 2 node buffers)
        size_t node_buf = (size_t)N_NODES * HID * sizeof(float);
        float* bufA = (float*)d_ws;
        float* bufB = (float*)((char*)d_ws + node_buf);
        long long scatter_work = (long long)n_edges * HID;
        int scatter_blocks = (int)((scatter_work + 255) / 256);
        gemm1f_kernel<<<num_node_blocks, 256, 0, stream>>>(x, W1, bufA);
        hipMemsetAsync(bufB, 0, node_buf, stream);
        scatter_kernel<<<scatter_blocks, 256, 0, stream>>>(bufA, esrc, edst, ew, bufB, n_edges);
        gemm2_kernel<<<num_node_blocks, 256, 0, stream>>>(bufB, b1, W2, bufA);
        hipMemsetAsync(bufB, 0, node_buf, stream);
        scatter_kernel<<<scatter_blocks, 256, 0, stream>>>(bufA, esrc, edst, ew, bufB, n_edges);
        final_kernel<<<num_node_blocks, 256, 0, stream>>>(bufB, b2, Wd, bd, out);
    }
}

// Round 5
// 756.292 us; speedup vs baseline: 1.9104x; 1.9104x over previous
//
#include <hip/hip_runtime.h>
#include <hip/hip_fp16.h>

#define N_NODES 200000
#define F_IN 128
#define HID 16
#define NWIN 8
#define WIN_NODES (N_NODES / NWIN)    // 25000
#define NSEG 256                      // edge segments for fill
#define SCAN_BLOCKS ((N_NODES + 255) / 256)   // 782

// ---------------- Stage 1: h = x @ W1 -> fp16 [N,16] -----------------------
__global__ __launch_bounds__(256) void gemm1_kernel(const float* __restrict__ x,
                                                    const float* __restrict__ W1,
                                                    __half* __restrict__ h) {
    __shared__ float w[F_IN * HID];  // 8 KB
    int tid = threadIdx.x;
    for (int i = tid; i < F_IN * HID; i += 256) w[i] = W1[i];
    __syncthreads();

    int row = blockIdx.x * 256 + tid;
    if (row >= N_NODES) return;

    float acc[HID];
#pragma unroll
    for (int j = 0; j < HID; j++) acc[j] = 0.f;

    const float4* xr = reinterpret_cast<const float4*>(x + (size_t)row * F_IN);
#pragma unroll 4
    for (int k4 = 0; k4 < F_IN / 4; k4++) {
        float4 xv = xr[k4];
        const float* wr = &w[k4 * 4 * HID];
#pragma unroll
        for (int j = 0; j < HID; j++) acc[j] += xv.x * wr[j];
#pragma unroll
        for (int j = 0; j < HID; j++) acc[j] += xv.y * wr[HID + j];
#pragma unroll
        for (int j = 0; j < HID; j++) acc[j] += xv.z * wr[2 * HID + j];
#pragma unroll
        for (int j = 0; j < HID; j++) acc[j] += xv.w * wr[3 * HID + j];
    }

    union { __half hh[16]; uint4 u[2]; } pk;
#pragma unroll
    for (int j = 0; j < HID; j++) pk.hh[j] = __float2half(acc[j]);
    uint4* hr = reinterpret_cast<uint4*>(h + (size_t)row * HID);
    hr[0] = pk.u[0];
    hr[1] = pk.u[1];
}

// ---------------- CSR build: degree count ----------------------------------
__global__ __launch_bounds__(256) void count_kernel(const int* __restrict__ dst,
                                                    int* __restrict__ deg, int n_edges) {
    int e = blockIdx.x * 256 + threadIdx.x;
    if (e < n_edges) atomicAdd(&deg[dst[e]], 1);
}

// ---------------- 3-level exclusive scan over N_NODES ----------------------
__global__ __launch_bounds__(256) void scan1_kernel(const int* __restrict__ in,
                                                    int* __restrict__ out,
                                                    int* __restrict__ bsum, int n) {
    __shared__ int s[256];
    int t = threadIdx.x, i = blockIdx.x * 256 + t;
    int v = (i < n) ? in[i] : 0;
    s[t] = v; __syncthreads();
    for (int off = 1; off < 256; off <<= 1) {
        int u = (t >= off) ? s[t - off] : 0; __syncthreads();
        s[t] += u; __syncthreads();
    }
    if (i < n) out[i] = s[t] - v;  // block-local exclusive
    if (t == 255) bsum[blockIdx.x] = s[255];
}

__global__ __launch_bounds__(256) void scan2_kernel(int* __restrict__ bsum, int nb) {
    __shared__ int s[256];
    __shared__ int carry;
    int t = threadIdx.x;
    if (t == 0) carry = 0;
    __syncthreads();
    for (int base = 0; base < nb; base += 256) {
        int v = (base + t < nb) ? bsum[base + t] : 0;
        s[t] = v; __syncthreads();
        for (int off = 1; off < 256; off <<= 1) {
            int u = (t >= off) ? s[t - off] : 0; __syncthreads();
            s[t] += u; __syncthreads();
        }
        if (base + t < nb) bsum[base + t] = carry + s[t] - v;  // exclusive
        __syncthreads();
        if (t == 0) carry += s[255];
        __syncthreads();
    }
}

// finalize offsets; also init cursor copy
__global__ __launch_bounds__(256) void scan3_kernel(int* __restrict__ out,
                                                    int* __restrict__ cursor,
                                                    const int* __restrict__ bsum,
                                                    int n, int total) {
    int i = blockIdx.x * 256 + threadIdx.x;
    if (i < n) {
        int v = out[i] + bsum[blockIdx.x];
        out[i] = v;
        cursor[i] = v;
    }
    if (i == 0) out[n] = total;
}

// ---------------- Windowed CSR fill ----------------------------------------
// window = blockIdx.x & 7 (XCD round-robin heuristic -> window writes stay in
// one XCD's L2 and accumulate into full lines). seg = blockIdx.x >> 3 strides
// its private edge chunk; only edges whose dst falls in the window are placed.
__global__ __launch_bounds__(256) void fill_win_kernel(const int* __restrict__ src,
                                                       const int* __restrict__ dst,
                                                       const float* __restrict__ ew,
                                                       int* __restrict__ cursor,
                                                       int2* __restrict__ recs,
                                                       int n_edges, int chunk) {
    int win = blockIdx.x & (NWIN - 1);
    int seg = blockIdx.x >> 3;
    int lo = win * WIN_NODES, hi = lo + WIN_NODES;
    int e0 = seg * chunk;
    int e1 = e0 + chunk; if (e1 > n_edges) e1 = n_edges;
    for (int e = e0 + threadIdx.x; e < e1; e += 256) {
        int d = dst[e];
        if (d >= lo && d < hi) {
            int pos = atomicAdd(&cursor[d], 1);
            recs[pos] = make_int2(src[e], __float_as_int(ew[e]));
        }
    }
}

// ---------------- Layer-1 aggregation (CSR, register acc) + relu/b1 + W2 ---
// 16 lanes per node; 256 threads = 16 nodes/block; unroll-4 gather chains.
__global__ __launch_bounds__(256) void agg_mid_kernel(const __half* __restrict__ h,
                                                      const int* __restrict__ off,
                                                      const int2* __restrict__ recs,
                                                      const float* __restrict__ b1,
                                                      const float* __restrict__ W2,
                                                      __half* __restrict__ h2) {
    __shared__ float wm[HID * HID];
    __shared__ float bs[HID];
    int t = threadIdx.x;
    if (t < HID * HID) wm[t] = W2[t];
    if (t < HID) bs[t] = b1[t];
    __syncthreads();

    int node = blockIdx.x * 16 + (t >> 4);
    int lane = t & 15;
    if (node >= N_NODES) return;

    int beg = off[node];
    int end = off[node + 1];
    float acc = 0.f;
    int p = beg;
    for (; p + 4 <= end; p += 4) {
        int2 e0 = recs[p], e1 = recs[p + 1], e2 = recs[p + 2], e3 = recs[p + 3];
        float v0 = __half2float(h[(size_t)e0.x * HID + lane]);
        float v1 = __half2float(h[(size_t)e1.x * HID + lane]);
        float v2 = __half2float(h[(size_t)e2.x * HID + lane]);
        float v3 = __half2float(h[(size_t)e3.x * HID + lane]);
        acc += v0 * __int_as_float(e0.y);
        acc += v1 * __int_as_float(e1.y);
        acc += v2 * __int_as_float(e2.y);
        acc += v3 * __int_as_float(e3.y);
    }
    for (; p < end; ++p) {
        int2 e = recs[p];
        acc += __half2float(h[(size_t)e.x * HID + lane]) * __int_as_float(e.y);
    }
    float hv = fmaxf(acc + bs[lane], 0.f);

    // h2[node][lane] = sum_k hv_k * W2[k][lane] via intra-wave shuffle
    int gbase = (t & 63) & ~15;
    float acc2 = 0.f;
#pragma unroll
    for (int k = 0; k < HID; k++) {
        float hk = __shfl(hv, gbase + k, 64);
        acc2 += hk * wm[k * HID + lane];
    }
    h2[(size_t)node * HID + lane] = __float2half(acc2);
}

// ---------------- Layer-2 aggregation + relu/b2 + Wd + bd ------------------
__global__ __launch_bounds__(256) void agg_final_kernel(const __half* __restrict__ h2,
                                                        const int* __restrict__ off,
                                                        const int2* __restrict__ recs,
                                                        const float* __restrict__ b2,
                                                        const float* __restrict__ Wd,
                                                        const float* __restrict__ bd,
                                                        float* __restrict__ out) {
    __shared__ float wd[HID];
    __shared__ float bs[HID];
    __shared__ float bdv;
    int t = threadIdx.x;
    if (t < HID) { wd[t] = Wd[t]; bs[t] = b2[t]; }
    if (t == 0) bdv = bd[0];
    __syncthreads();

    int node = blockIdx.x * 16 + (t >> 4);
    int lane = t & 15;
    if (node >= N_NODES) return;

    int beg = off[node];
    int end = off[node + 1];
    float acc = 0.f;
    int p = beg;
    for (; p + 4 <= end; p += 4) {
        int2 e0 = recs[p], e1 = recs[p + 1], e2 = recs[p + 2], e3 = recs[p + 3];
        float v0 = __half2float(h2[(size_t)e0.x * HID + lane]);
        float v1 = __half2float(h2[(size_t)e1.x * HID + lane]);
        float v2 = __half2float(h2[(size_t)e2.x * HID + lane]);
        float v3 = __half2float(h2[(size_t)e3.x * HID + lane]);
        acc += v0 * __int_as_float(e0.y);
        acc += v1 * __int_as_float(e1.y);
        acc += v2 * __int_as_float(e2.y);
        acc += v3 * __int_as_float(e3.y);
    }
    for (; p < end; ++p) {
        int2 e = recs[p];
        acc += __half2float(h2[(size_t)e.x * HID + lane]) * __int_as_float(e.y);
    }
    float v = fmaxf(acc + bs[lane], 0.f) * wd[lane];
#pragma unroll
    for (int o = 8; o; o >>= 1) v += __shfl_xor(v, o, 64);
    if (lane == 0) out[node] = v + bdv;
}

// =================== Fallback path (R1, fp32): atomic scatter ===============
__global__ __launch_bounds__(256) void gemm1f_kernel(const float* __restrict__ x,
                                                     const float* __restrict__ W1,
                                                     float* __restrict__ h) {
    __shared__ float w[F_IN * HID];
    int tid = threadIdx.x;
    for (int i = tid; i < F_IN * HID; i += 256) w[i] = W1[i];
    __syncthreads();
    int row = blockIdx.x * 256 + tid;
    if (row >= N_NODES) return;
    float acc[HID];
#pragma unroll
    for (int j = 0; j < HID; j++) acc[j] = 0.f;
    const float4* xr = reinterpret_cast<const float4*>(x + (size_t)row * F_IN);
#pragma unroll 4
    for (int k4 = 0; k4 < F_IN / 4; k4++) {
        float4 xv = xr[k4];
        const float* wr = &w[k4 * 4 * HID];
#pragma unroll
        for (int j = 0; j < HID; j++) acc[j] += xv.x * wr[j];
#pragma unroll
        for (int j = 0; j < HID; j++) acc[j] += xv.y * wr[HID + j];
#pragma unroll
        for (int j = 0; j < HID; j++) acc[j] += xv.z * wr[2 * HID + j];
#pragma unroll
        for (int j = 0; j < HID; j++) acc[j] += xv.w * wr[3 * HID + j];
    }
    float4* hr = reinterpret_cast<float4*>(h + (size_t)row * HID);
#pragma unroll
    for (int q = 0; q < HID / 4; q++)
        hr[q] = make_float4(acc[4 * q], acc[4 * q + 1], acc[4 * q + 2], acc[4 * q + 3]);
}

__global__ __launch_bounds__(256) void scatter_kernel(const float* __restrict__ h,
                                                      const int* __restrict__ src,
                                                      const int* __restrict__ dst,
                                                      const float* __restrict__ ew,
                                                      float* __restrict__ agg,
                                                      int n_edges) {
    long long idx = (long long)blockIdx.x * 256 + threadIdx.x;
    long long total = (long long)n_edges * HID;
    if (idx >= total) return;
    int e = (int)(idx >> 4);
    int j = (int)(idx & (HID - 1));
    float val = h[(size_t)src[e] * HID + j] * ew[e];
    atomicAdd(&agg[(size_t)dst[e] * HID + j], val);
}

__global__ __launch_bounds__(256) void gemm2_kernel(const float* __restrict__ agg,
                                                    const float* __restrict__ b1,
                                                    const float* __restrict__ W2,
                                                    float* __restrict__ h2) {
    __shared__ float w[HID * HID];
    __shared__ float bias[HID];
    int tid = threadIdx.x;
    if (tid < HID * HID) w[tid] = W2[tid];
    if (tid < HID) bias[tid] = b1[tid];
    __syncthreads();
    int row = blockIdx.x * 256 + tid;
    if (row >= N_NODES) return;
    float hv[HID];
    const float4* ar = reinterpret_cast<const float4*>(agg + (size_t)row * HID);
#pragma unroll
    for (int q = 0; q < 4; q++) {
        float4 v = ar[q];
        hv[4 * q + 0] = fmaxf(v.x + bias[4 * q + 0], 0.f);
        hv[4 * q + 1] = fmaxf(v.y + bias[4 * q + 1], 0.f);
        hv[4 * q + 2] = fmaxf(v.z + bias[4 * q + 2], 0.f);
        hv[4 * q + 3] = fmaxf(v.w + bias[4 * q + 3], 0.f);
    }
    float acc[HID];
#pragma unroll
    for (int j = 0; j < HID; j++) acc[j] = 0.f;
#pragma unroll
    for (int k = 0; k < HID; k++) {
        float hk = hv[k];
#pragma unroll
        for (int j = 0; j < HID; j++) acc[j] += hk * w[k * HID + j];
    }
    float4* hr = reinterpret_cast<float4*>(h2 + (size_t)row * HID);
#pragma unroll
    for (int q = 0; q < 4; q++)
        hr[q] = make_float4(acc[4 * q], acc[4 * q + 1], acc[4 * q + 2], acc[4 * q + 3]);
}

__global__ __launch_bounds__(256) void final_kernel(const float* __restrict__ agg,
                                                    const float* __restrict__ b2,
                                                    const float* __restrict__ Wd,
                                                    const float* __restrict__ bd,
                                                    float* __restrict__ out) {
    __shared__ float wd[HID];
    __shared__ float bias[HID];
    __shared__ float bdv;
    int tid = threadIdx.x;
    if (tid < HID) { wd[tid] = Wd[tid]; bias[tid] = b2[tid]; }
    if (tid == 0) bdv = bd[0];
    __syncthreads();
    int row = blockIdx.x * 256 + tid;
    if (row >= N_NODES) return;
    const float4* ar = reinterpret_cast<const float4*>(agg + (size_t)row * HID);
    float acc = bdv;
#pragma unroll
    for (int q = 0; q < 4; q++) {
        float4 v = ar[q];
        acc += fmaxf(v.x + bias[4 * q + 0], 0.f) * wd[4 * q + 0];
        acc += fmaxf(v.y + bias[4 * q + 1], 0.f) * wd[4 * q + 1];
        acc += fmaxf(v.z + bias[4 * q + 2], 0.f) * wd[4 * q + 2];
        acc += fmaxf(v.w + bias[4 * q + 3], 0.f) * wd[4 * q + 3];
    }
    out[row] = acc;
}

extern "C" void kernel_launch(void* const* d_in, const int* in_sizes, int n_in,
                              void* d_out, int out_size, void* d_ws, size_t ws_size,
                              hipStream_t stream) {
    const float* x    = (const float*)d_in[0];
    const int*   esrc = (const int*)d_in[1];
    const int*   edst = (const int*)d_in[2];
    const float* ew   = (const float*)d_in[3];
    const float* W1   = (const float*)d_in[4];
    const float* b1   = (const float*)d_in[5];
    const float* W2   = (const float*)d_in[6];
    const float* b2   = (const float*)d_in[7];
    const float* Wd   = (const float*)d_in[8];
    const float* bd   = (const float*)d_in[9];
    float* out = (float*)d_out;

    int n_edges = in_sizes[1];
    int num_node_blocks = (N_NODES + 255) / 256;

    // ---- workspace layout (fast path) ----
    size_t hbuf = (size_t)N_NODES * HID * sizeof(__half);      // 6.4 MB each
    size_t off_bytes = (((size_t)(N_NODES + 1) * 4 + 15) / 16) * 16;
    size_t cur_bytes = (((size_t)N_NODES * 4 + 15) / 16) * 16;
    size_t bsum_bytes = (((size_t)SCAN_BLOCKS * 4 + 15) / 16) * 16;
    size_t recs_bytes = (size_t)n_edges * 8;

    size_t needed = 2 * hbuf + off_bytes + cur_bytes + bsum_bytes + recs_bytes;

    if (ws_size >= needed && n_edges > 0) {
        char* p = (char*)d_ws;
        __half* h1   = (__half*)p;  p += hbuf;
        __half* h2   = (__half*)p;  p += hbuf;
        int* nodeoff = (int*)p;     p += off_bytes;
        int* cursor  = (int*)p;     p += cur_bytes;
        int* bsum    = (int*)p;     p += bsum_bytes;
        int2* recs   = (int2*)p;

        int edge_blocks = (n_edges + 255) / 256;
        int chunk = (n_edges + NSEG - 1) / NSEG;
        int agg_blocks = (N_NODES + 15) / 16;

        gemm1_kernel<<<num_node_blocks, 256, 0, stream>>>(x, W1, h1);

        // CSR build: count -> scan -> windowed fill
        hipMemsetAsync(cursor, 0, (size_t)N_NODES * 4, stream);
        count_kernel<<<edge_blocks, 256, 0, stream>>>(edst, cursor, n_edges);
        scan1_kernel<<<SCAN_BLOCKS, 256, 0, stream>>>(cursor, nodeoff, bsum, N_NODES);
        scan2_kernel<<<1, 256, 0, stream>>>(bsum, SCAN_BLOCKS);
        scan3_kernel<<<SCAN_BLOCKS, 256, 0, stream>>>(nodeoff, cursor, bsum,
                                                      N_NODES, n_edges);
        fill_win_kernel<<<NSEG * NWIN, 256, 0, stream>>>(esrc, edst, ew, cursor,
                                                         recs, n_edges, chunk);

        agg_mid_kernel<<<agg_blocks, 256, 0, stream>>>(h1, nodeoff, recs, b1, W2, h2);
        agg_final_kernel<<<agg_blocks, 256, 0, stream>>>(h2, nodeoff, recs, b2, Wd, bd, out);
    } else {
        // Fallback: R1 atomic path (fp32, needs only 2 node buffers)
        size_t node_buf = (size_t)N_NODES * HID * sizeof(float);
        float* bufA = (float*)d_ws;
        float* bufB = (float*)((char*)d_ws + node_buf);
        long long scatter_work = (long long)n_edges * HID;
        int scatter_blocks = (int)((scatter_work + 255) / 256);
        gemm1f_kernel<<<num_node_blocks, 256, 0, stream>>>(x, W1, bufA);
        hipMemsetAsync(bufB, 0, node_buf, stream);
        scatter_kernel<<<scatter_blocks, 256, 0, stream>>>(bufA, esrc, edst, ew, bufB, n_edges);
        gemm2_kernel<<<num_node_blocks, 256, 0, stream>>>(bufB, b1, W2, bufA);
        hipMemsetAsync(bufB, 0, node_buf, stream);
        scatter_kernel<<<scatter_blocks, 256, 0, stream>>>(bufA, esrc, edst, ew, bufB, n_edges);
        final_kernel<<<num_node_blocks, 256, 0, stream>>>(bufB, b2, Wd, bd, out);
    }
}

// Round 6
// 280.110 us; speedup vs baseline: 5.1580x; 2.7000x over previous
//
#include <hip/hip_runtime.h>
#include <hip/hip_fp16.h>

#define N_NODES 200000
#define F_IN 128
#define HID 16
#define SHIFT 7
#define BKT_NODES 128                 // 1 << SHIFT
#define NB 1563                       // ceil(N_NODES / 128)
#define NBLK 256                      // hist/partition grid size
#define BLKT 512                      // hist/partition block threads
#define M_SCAN (NB * NBLK)            // 400128 (divisible by 256)
#define CAP 4608                      // recs per in-LDS sort chunk (36 KB)
#define AGG_T 512                     // agg block threads
#define NGRP (AGG_T / 16)             // 32 node-groups per pass
#define NPASS (BKT_NODES / NGRP)      // 4 passes cover 128 nodes

// ---------------- Stage 1: h = x @ W1 -> fp16 [N,16] -----------------------
__global__ __launch_bounds__(256) void gemm1_kernel(const float* __restrict__ x,
                                                    const float* __restrict__ W1,
                                                    __half* __restrict__ h) {
    __shared__ float w[F_IN * HID];  // 8 KB
    int tid = threadIdx.x;
    for (int i = tid; i < F_IN * HID; i += 256) w[i] = W1[i];
    __syncthreads();

    int row = blockIdx.x * 256 + tid;
    if (row >= N_NODES) return;

    float acc[HID];
#pragma unroll
    for (int j = 0; j < HID; j++) acc[j] = 0.f;

    const float4* xr = reinterpret_cast<const float4*>(x + (size_t)row * F_IN);
#pragma unroll 4
    for (int k4 = 0; k4 < F_IN / 4; k4++) {
        float4 xv = xr[k4];
        const float* wr = &w[k4 * 4 * HID];
#pragma unroll
        for (int j = 0; j < HID; j++) acc[j] += xv.x * wr[j];
#pragma unroll
        for (int j = 0; j < HID; j++) acc[j] += xv.y * wr[HID + j];
#pragma unroll
        for (int j = 0; j < HID; j++) acc[j] += xv.z * wr[2 * HID + j];
#pragma unroll
        for (int j = 0; j < HID; j++) acc[j] += xv.w * wr[3 * HID + j];
    }

    union { __half hh[16]; uint4 u[2]; } pk;
#pragma unroll
    for (int j = 0; j < HID; j++) pk.hh[j] = __float2half(acc[j]);
    uint4* hr = reinterpret_cast<uint4*>(h + (size_t)row * HID);
    hr[0] = pk.u[0];
    hr[1] = pk.u[1];
}

// ---------------- Bucket histogram: hist[b][blk] ----------------------------
__global__ __launch_bounds__(BLKT) void hist_kernel(const int* __restrict__ dst,
                                                    int* __restrict__ hist,
                                                    int n_edges, int chunk) {
    __shared__ int hc[NB];  // 6.3 KB
    int t = threadIdx.x, blk = blockIdx.x;
    for (int i = t; i < NB; i += BLKT) hc[i] = 0;
    __syncthreads();
    int e0 = blk * chunk;
    int e1 = e0 + chunk; if (e1 > n_edges) e1 = n_edges;
    for (int e = e0 + t; e < e1; e += BLKT)
        atomicAdd(&hc[dst[e] >> SHIFT], 1);
    __syncthreads();
    for (int b = t; b < NB; b += BLKT) hist[b * NBLK + blk] = hc[b];
}

// ---------------- 3-level exclusive scan over M_SCAN elements ---------------
__global__ __launch_bounds__(256) void scan1_kernel(const int* __restrict__ in,
                                                    int* __restrict__ out,
                                                    int* __restrict__ bsum, int n) {
    __shared__ int s[256];
    int t = threadIdx.x, i = blockIdx.x * 256 + t;
    int v = (i < n) ? in[i] : 0;
    s[t] = v; __syncthreads();
    for (int off = 1; off < 256; off <<= 1) {
        int u = (t >= off) ? s[t - off] : 0; __syncthreads();
        s[t] += u; __syncthreads();
    }
    if (i < n) out[i] = s[t] - v;  // block-local exclusive
    if (t == 255) bsum[blockIdx.x] = s[255];
}

__global__ __launch_bounds__(256) void scan2_kernel(int* __restrict__ bsum, int nb) {
    __shared__ int s[256];
    __shared__ int carry;
    int t = threadIdx.x;
    if (t == 0) carry = 0;
    __syncthreads();
    for (int base = 0; base < nb; base += 256) {
        int v = (base + t < nb) ? bsum[base + t] : 0;
        s[t] = v; __syncthreads();
        for (int off = 1; off < 256; off <<= 1) {
            int u = (t >= off) ? s[t - off] : 0; __syncthreads();
            s[t] += u; __syncthreads();
        }
        if (base + t < nb) bsum[base + t] = carry + s[t] - v;  // exclusive
        __syncthreads();
        if (t == 0) carry += s[255];
        __syncthreads();
    }
}

__global__ __launch_bounds__(256) void scan3_kernel(int* __restrict__ out,
                                                    const int* __restrict__ bsum,
                                                    int n, int total) {
    int i = blockIdx.x * 256 + threadIdx.x;
    if (i < n) out[i] += bsum[blockIdx.x];
    if (i == 0) out[n] = total;
}

// ---------------- Partition: bucket-grouped records (block-private ranges) --
// record: {src | local_dst<<18, weight_bits}  (src < 2^18, local_dst < 2^7)
__global__ __launch_bounds__(BLKT) void partition_kernel(const int* __restrict__ src,
                                                         const int* __restrict__ dst,
                                                         const float* __restrict__ ew,
                                                         const int* __restrict__ scanned,
                                                         int2* __restrict__ recs,
                                                         int n_edges, int chunk) {
    __shared__ int cur[NB];
    int t = threadIdx.x, blk = blockIdx.x;
    for (int b = t; b < NB; b += BLKT) cur[b] = scanned[b * NBLK + blk];
    __syncthreads();
    int e0 = blk * chunk;
    int e1 = e0 + chunk; if (e1 > n_edges) e1 = n_edges;
    for (int e = e0 + t; e < e1; e += BLKT) {
        int d = dst[e];
        int b = d >> SHIFT;
        int pos = atomicAdd(&cur[b], 1);  // LDS atomic, block-private range
        recs[pos] = make_int2(src[e] | ((d & (BKT_NODES - 1)) << 18),
                              __float_as_int(ew[e]));
    }
}

// ---------------- Aggregation: in-LDS counting sort + register acc ----------
// One block per bucket. Sort chunk (<=CAP recs) by local dst in LDS, then
// 16 lanes per node accumulate in registers with unroll-8 gather chains.
// layer 1 epilogue: h2 = relu(agg + b1) @ W2 (fp16 out)
__global__ __launch_bounds__(AGG_T) void agg_mid_kernel(const __half* __restrict__ h,
                                                        const int* __restrict__ scanned,
                                                        const int2* __restrict__ recs,
                                                        const float* __restrict__ b1,
                                                        const float* __restrict__ W2,
                                                        __half* __restrict__ h2) {
    __shared__ int2 srt[CAP];            // 36 KB
    __shared__ int cnt[BKT_NODES];
    __shared__ int offs[BKT_NODES + 1];
    __shared__ int curs[BKT_NODES];
    __shared__ float wm[HID * HID];
    __shared__ float bs[HID];
    int t = threadIdx.x, bkt = blockIdx.x;
    if (t < HID * HID) wm[t] = W2[t];
    if (t < HID) bs[t] = b1[t];
    __syncthreads();

    int beg = scanned[bkt * NBLK];
    int end = scanned[(bkt + 1) * NBLK];
    int lane = t & 15, grp = t >> 4;

    float acc[NPASS];
#pragma unroll
    for (int i = 0; i < NPASS; i++) acc[i] = 0.f;

    for (int c0 = beg; c0 < end; c0 += CAP) {
        int n = end - c0; if (n > CAP) n = CAP;
        for (int i = t; i < BKT_NODES; i += AGG_T) cnt[i] = 0;
        __syncthreads();
        for (int i = t; i < n; i += AGG_T)
            atomicAdd(&cnt[((unsigned)recs[c0 + i].x) >> 18], 1);
        __syncthreads();
        if (t == 0) {
            int run = 0;
            for (int k = 0; k < BKT_NODES; k++) { offs[k] = run; run += cnt[k]; }
            offs[BKT_NODES] = run;
        }
        __syncthreads();
        for (int i = t; i < BKT_NODES; i += AGG_T) curs[i] = offs[i];
        __syncthreads();
        for (int i = t; i < n; i += AGG_T) {
            int2 r = recs[c0 + i];
            int ld = ((unsigned)r.x) >> 18;
            srt[atomicAdd(&curs[ld], 1)] = r;
        }
        __syncthreads();

#pragma unroll
        for (int it = 0; it < NPASS; it++) {
            int ld = it * NGRP + grp;
            int pb = offs[ld], pe = offs[ld + 1];
            float a = 0.f;
            int p = pb;
            for (; p + 8 <= pe; p += 8) {
                float v[8], w[8];
#pragma unroll
                for (int u = 0; u < 8; u++) {
                    int2 r = srt[p + u];
                    w[u] = __int_as_float(r.y);
                    v[u] = __half2float(h[(size_t)(r.x & 0x3FFFF) * HID + lane]);
                }
#pragma unroll
                for (int u = 0; u < 8; u++) a += v[u] * w[u];
            }
            for (; p < pe; ++p) {
                int2 r = srt[p];
                a += __half2float(h[(size_t)(r.x & 0x3FFFF) * HID + lane]) *
                     __int_as_float(r.y);
            }
            acc[it] += a;
        }
        __syncthreads();  // protect srt/offs before next chunk
    }

    // epilogue: relu(acc + b1) @ W2 via intra-wave shuffle
    int gbase = (t & 63) & ~15;
#pragma unroll
    for (int it = 0; it < NPASS; it++) {
        int node = bkt * BKT_NODES + it * NGRP + grp;
        float hv = fmaxf(acc[it] + bs[lane], 0.f);
        float o = 0.f;
#pragma unroll
        for (int k = 0; k < HID; k++)
            o += __shfl(hv, gbase + k, 64) * wm[k * HID + lane];
        if (node < N_NODES)
            h2[(size_t)node * HID + lane] = __float2half(o);
    }
}

// layer 2 epilogue: out = relu(agg + b2) @ Wd + bd (fp32 out)
__global__ __launch_bounds__(AGG_T) void agg_final_kernel(const __half* __restrict__ h2,
                                                          const int* __restrict__ scanned,
                                                          const int2* __restrict__ recs,
                                                          const float* __restrict__ b2,
                                                          const float* __restrict__ Wd,
                                                          const float* __restrict__ bd,
                                                          float* __restrict__ out) {
    __shared__ int2 srt[CAP];
    __shared__ int cnt[BKT_NODES];
    __shared__ int offs[BKT_NODES + 1];
    __shared__ int curs[BKT_NODES];
    __shared__ float wd[HID];
    __shared__ float bs[HID];
    __shared__ float bdv;
    int t = threadIdx.x, bkt = blockIdx.x;
    if (t < HID) { wd[t] = Wd[t]; bs[t] = b2[t]; }
    if (t == 0) bdv = bd[0];
    __syncthreads();

    int beg = scanned[bkt * NBLK];
    int end = scanned[(bkt + 1) * NBLK];
    int lane = t & 15, grp = t >> 4;

    float acc[NPASS];
#pragma unroll
    for (int i = 0; i < NPASS; i++) acc[i] = 0.f;

    for (int c0 = beg; c0 < end; c0 += CAP) {
        int n = end - c0; if (n > CAP) n = CAP;
        for (int i = t; i < BKT_NODES; i += AGG_T) cnt[i] = 0;
        __syncthreads();
        for (int i = t; i < n; i += AGG_T)
            atomicAdd(&cnt[((unsigned)recs[c0 + i].x) >> 18], 1);
        __syncthreads();
        if (t == 0) {
            int run = 0;
            for (int k = 0; k < BKT_NODES; k++) { offs[k] = run; run += cnt[k]; }
            offs[BKT_NODES] = run;
        }
        __syncthreads();
        for (int i = t; i < BKT_NODES; i += AGG_T) curs[i] = offs[i];
        __syncthreads();
        for (int i = t; i < n; i += AGG_T) {
            int2 r = recs[c0 + i];
            int ld = ((unsigned)r.x) >> 18;
            srt[atomicAdd(&curs[ld], 1)] = r;
        }
        __syncthreads();

#pragma unroll
        for (int it = 0; it < NPASS; it++) {
            int ld = it * NGRP + grp;
            int pb = offs[ld], pe = offs[ld + 1];
            float a = 0.f;
            int p = pb;
            for (; p + 8 <= pe; p += 8) {
                float v[8], w[8];
#pragma unroll
                for (int u = 0; u < 8; u++) {
                    int2 r = srt[p + u];
                    w[u] = __int_as_float(r.y);
                    v[u] = __half2float(h2[(size_t)(r.x & 0x3FFFF) * HID + lane]);
                }
#pragma unroll
                for (int u = 0; u < 8; u++) a += v[u] * w[u];
            }
            for (; p < pe; ++p) {
                int2 r = srt[p];
                a += __half2float(h2[(size_t)(r.x & 0x3FFFF) * HID + lane]) *
                     __int_as_float(r.y);
            }
            acc[it] += a;
        }
        __syncthreads();
    }

#pragma unroll
    for (int it = 0; it < NPASS; it++) {
        int node = bkt * BKT_NODES + it * NGRP + grp;
        float v = fmaxf(acc[it] + bs[lane], 0.f) * wd[lane];
#pragma unroll
        for (int o = 8; o; o >>= 1) v += __shfl_xor(v, o, 64);
        if (lane == 0 && node < N_NODES) out[node] = v + bdv;
    }
}

// =================== Fallback path (R1, fp32): atomic scatter ===============
__global__ __launch_bounds__(256) void gemm1f_kernel(const float* __restrict__ x,
                                                     const float* __restrict__ W1,
                                                     float* __restrict__ h) {
    __shared__ float w[F_IN * HID];
    int tid = threadIdx.x;
    for (int i = tid; i < F_IN * HID; i += 256) w[i] = W1[i];
    __syncthreads();
    int row = blockIdx.x * 256 + tid;
    if (row >= N_NODES) return;
    float acc[HID];
#pragma unroll
    for (int j = 0; j < HID; j++) acc[j] = 0.f;
    const float4* xr = reinterpret_cast<const float4*>(x + (size_t)row * F_IN);
#pragma unroll 4
    for (int k4 = 0; k4 < F_IN / 4; k4++) {
        float4 xv = xr[k4];
        const float* wr = &w[k4 * 4 * HID];
#pragma unroll
        for (int j = 0; j < HID; j++) acc[j] += xv.x * wr[j];
#pragma unroll
        for (int j = 0; j < HID; j++) acc[j] += xv.y * wr[HID + j];
#pragma unroll
        for (int j = 0; j < HID; j++) acc[j] += xv.z * wr[2 * HID + j];
#pragma unroll
        for (int j = 0; j < HID; j++) acc[j] += xv.w * wr[3 * HID + j];
    }
    float4* hr = reinterpret_cast<float4*>(h + (size_t)row * HID);
#pragma unroll
    for (int q = 0; q < HID / 4; q++)
        hr[q] = make_float4(acc[4 * q], acc[4 * q + 1], acc[4 * q + 2], acc[4 * q + 3]);
}

__global__ __launch_bounds__(256) void scatter_kernel(const float* __restrict__ h,
                                                      const int* __restrict__ src,
                                                      const int* __restrict__ dst,
                                                      const float* __restrict__ ew,
                                                      float* __restrict__ agg,
                                                      int n_edges) {
    long long idx = (long long)blockIdx.x * 256 + threadIdx.x;
    long long total = (long long)n_edges * HID;
    if (idx >= total) return;
    int e = (int)(idx >> 4);
    int j = (int)(idx & (HID - 1));
    float val = h[(size_t)src[e] * HID + j] * ew[e];
    atomicAdd(&agg[(size_t)dst[e] * HID + j], val);
}

__global__ __launch_bounds__(256) void gemm2_kernel(const float* __restrict__ agg,
                                                    const float* __restrict__ b1,
                                                    const float* __restrict__ W2,
                                                    float* __restrict__ h2) {
    __shared__ float w[HID * HID];
    __shared__ float bias[HID];
    int tid = threadIdx.x;
    if (tid < HID * HID) w[tid] = W2[tid];
    if (tid < HID) bias[tid] = b1[tid];
    __syncthreads();
    int row = blockIdx.x * 256 + tid;
    if (row >= N_NODES) return;
    float hv[HID];
    const float4* ar = reinterpret_cast<const float4*>(agg + (size_t)row * HID);
#pragma unroll
    for (int q = 0; q < 4; q++) {
        float4 v = ar[q];
        hv[4 * q + 0] = fmaxf(v.x + bias[4 * q + 0], 0.f);
        hv[4 * q + 1] = fmaxf(v.y + bias[4 * q + 1], 0.f);
        hv[4 * q + 2] = fmaxf(v.z + bias[4 * q + 2], 0.f);
        hv[4 * q + 3] = fmaxf(v.w + bias[4 * q + 3], 0.f);
    }
    float acc[HID];
#pragma unroll
    for (int j = 0; j < HID; j++) acc[j] = 0.f;
#pragma unroll
    for (int k = 0; k < HID; k++) {
        float hk = hv[k];
#pragma unroll
        for (int j = 0; j < HID; j++) acc[j] += hk * w[k * HID + j];
    }
    float4* hr = reinterpret_cast<float4*>(h2 + (size_t)row * HID);
#pragma unroll
    for (int q = 0; q < 4; q++)
        hr[q] = make_float4(acc[4 * q], acc[4 * q + 1], acc[4 * q + 2], acc[4 * q + 3]);
}

__global__ __launch_bounds__(256) void final_kernel(const float* __restrict__ agg,
                                                    const float* __restrict__ b2,
                                                    const float* __restrict__ Wd,
                                                    const float* __restrict__ bd,
                                                    float* __restrict__ out) {
    __shared__ float wd[HID];
    __shared__ float bias[HID];
    __shared__ float bdv;
    int tid = threadIdx.x;
    if (tid < HID) { wd[tid] = Wd[tid]; bias[tid] = b2[tid]; }
    if (tid == 0) bdv = bd[0];
    __syncthreads();
    int row = blockIdx.x * 256 + tid;
    if (row >= N_NODES) return;
    const float4* ar = reinterpret_cast<const float4*>(agg + (size_t)row * HID);
    float acc = bdv;
#pragma unroll
    for (int q = 0; q < 4; q++) {
        float4 v = ar[q];
        acc += fmaxf(v.x + bias[4 * q + 0], 0.f) * wd[4 * q + 0];
        acc += fmaxf(v.y + bias[4 * q + 1], 0.f) * wd[4 * q + 1];
        acc += fmaxf(v.z + bias[4 * q + 2], 0.f) * wd[4 * q + 2];
        acc += fmaxf(v.w + bias[4 * q + 3], 0.f) * wd[4 * q + 3];
    }
    out[row] = acc;
}

extern "C" void kernel_launch(void* const* d_in, const int* in_sizes, int n_in,
                              void* d_out, int out_size, void* d_ws, size_t ws_size,
                              hipStream_t stream) {
    const float* x    = (const float*)d_in[0];
    const int*   esrc = (const int*)d_in[1];
    const int*   edst = (const int*)d_in[2];
    const float* ew   = (const float*)d_in[3];
    const float* W1   = (const float*)d_in[4];
    const float* b1   = (const float*)d_in[5];
    const float* W2   = (const float*)d_in[6];
    const float* b2   = (const float*)d_in[7];
    const float* Wd   = (const float*)d_in[8];
    const float* bd   = (const float*)d_in[9];
    float* out = (float*)d_out;

    int n_edges = in_sizes[1];
    int num_node_blocks = (N_NODES + 255) / 256;

    // ---- workspace layout (fast path) ----
    size_t hbuf = (size_t)N_NODES * HID * sizeof(__half);      // 6.4 MB each
    size_t hist_bytes = (size_t)M_SCAN * 4;                    // 1.6 MB
    size_t scan_bytes = (((size_t)M_SCAN + 1) * 4 + 15) / 16 * 16;
    int scan_blocks = M_SCAN / 256;                            // 1563
    size_t bsum_bytes = (((size_t)scan_blocks * 4 + 15) / 16) * 16;
    size_t recs_bytes = (size_t)n_edges * 8;                   // 51.2 MB

    size_t needed = 2 * hbuf + hist_bytes + scan_bytes + bsum_bytes + recs_bytes;

    if (ws_size >= needed && n_edges > 0) {
        char* p = (char*)d_ws;
        __half* h1   = (__half*)p;  p += hbuf;
        __half* h2   = (__half*)p;  p += hbuf;
        int* hist    = (int*)p;     p += hist_bytes;
        int* scanned = (int*)p;     p += scan_bytes;
        int* bsum    = (int*)p;     p += bsum_bytes;
        int2* recs   = (int2*)p;

        int chunk = (n_edges + NBLK - 1) / NBLK;

        gemm1_kernel<<<num_node_blocks, 256, 0, stream>>>(x, W1, h1);

        hist_kernel<<<NBLK, BLKT, 0, stream>>>(edst, hist, n_edges, chunk);
        scan1_kernel<<<scan_blocks, 256, 0, stream>>>(hist, scanned, bsum, M_SCAN);
        scan2_kernel<<<1, 256, 0, stream>>>(bsum, scan_blocks);
        scan3_kernel<<<scan_blocks, 256, 0, stream>>>(scanned, bsum, M_SCAN, n_edges);
        partition_kernel<<<NBLK, BLKT, 0, stream>>>(esrc, edst, ew, scanned, recs,
                                                    n_edges, chunk);

        agg_mid_kernel<<<NB, AGG_T, 0, stream>>>(h1, scanned, recs, b1, W2, h2);
        agg_final_kernel<<<NB, AGG_T, 0, stream>>>(h2, scanned, recs, b2, Wd, bd, out);
    } else {
        // Fallback: R1 atomic path (fp32, needs only 2 node buffers)
        size_t node_buf = (size_t)N_NODES * HID * sizeof(float);
        float* bufA = (float*)d_ws;
        float* bufB = (float*)((char*)d_ws + node_buf);
        long long scatter_work = (long long)n_edges * HID;
        int scatter_blocks = (int)((scatter_work + 255) / 256);
        gemm1f_kernel<<<num_node_blocks, 256, 0, stream>>>(x, W1, bufA);
        hipMemsetAsync(bufB, 0, node_buf, stream);
        scatter_kernel<<<scatter_blocks, 256, 0, stream>>>(bufA, esrc, edst, ew, bufB, n_edges);
        gemm2_kernel<<<num_node_blocks, 256, 0, stream>>>(bufB, b1, W2, bufA);
        hipMemsetAsync(bufB, 0, node_buf, stream);
        scatter_kernel<<<scatter_blocks, 256, 0, stream>>>(bufA, esrc, edst, ew, bufB, n_edges);
        final_kernel<<<num_node_blocks, 256, 0, stream>>>(bufB, b2, Wd, bd, out);
    }
}